// Round 10
// baseline (650.204 us; speedup 1.0000x reference)
//
#include <hip/hip_runtime.h>

#define N_ 32768
#define K_ 4096
#define NC_ 4
#define D_ 256

using floatx4 = __attribute__((ext_vector_type(4))) float;
using bf16x8  = __attribute__((ext_vector_type(8))) short;

__device__ __forceinline__ unsigned short f2bf(float f) {
  union { float f; unsigned u; } a;
  a.f = f;
  unsigned u = a.u;
  u += 0x7fffu + ((u >> 16) & 1u);  // round-to-nearest-even
  return (unsigned short)(u >> 16);
}

__device__ __forceinline__ void async_copy16(void* lds, const void* g) {
  __builtin_amdgcn_global_load_lds(
      (__attribute__((address_space(1))) void*)(g),
      (__attribute__((address_space(3))) void*)(lds),
      16, 0, 0);
}

// ---------------- prep kernels: bf16 conversion + weighted row norms --------
template <bool WRITE_BF>
__global__ void prep_x_kern(const float* __restrict__ x, const float* __restrict__ sd,
                            unsigned short* __restrict__ xb, float* __restrict__ xsq) {
  const int lane = threadIdx.x & 63;
  const int row  = blockIdx.x * 4 + (threadIdx.x >> 6);
  const float4 xv = reinterpret_cast<const float4*>(x + (size_t)row * D_)[lane];
  const float4 sv = reinterpret_cast<const float4*>(sd)[lane];
  const float i0 = 1.0f / sv.x, i1 = 1.0f / sv.y, i2 = 1.0f / sv.z, i3 = 1.0f / sv.w;
  float s = xv.x * xv.x * i0 + xv.y * xv.y * i1 + xv.z * xv.z * i2 + xv.w * xv.w * i3;
  if (WRITE_BF) {
    union { unsigned short u[4]; uint2 v; } p;
    p.u[0] = f2bf(xv.x); p.u[1] = f2bf(xv.y); p.u[2] = f2bf(xv.z); p.u[3] = f2bf(xv.w);
    reinterpret_cast<uint2*>(xb)[(size_t)row * 64 + lane] = p.v;
  }
#pragma unroll
  for (int off = 32; off > 0; off >>= 1) s += __shfl_down(s, off, 64);
  if (lane == 0) xsq[row] = s;
}

template <bool WRITE_BF>
__global__ void prep_mu_kern(const float* __restrict__ mu, const float* __restrict__ sd,
                             unsigned short* __restrict__ bb, float* __restrict__ musq) {
  const int lane = threadIdx.x & 63;
  const int row  = blockIdx.x * 4 + (threadIdx.x >> 6);
  const float4 mv = reinterpret_cast<const float4*>(mu + (size_t)row * (NC_ * D_))[lane];
  const float4 sv = reinterpret_cast<const float4*>(sd)[lane];
  const float i0 = 1.0f / sv.x, i1 = 1.0f / sv.y, i2 = 1.0f / sv.z, i3 = 1.0f / sv.w;
  float s = mv.x * mv.x * i0 + mv.y * mv.y * i1 + mv.z * mv.z * i2 + mv.w * mv.w * i3;
  if (WRITE_BF) {
    union { unsigned short u[4]; uint2 v; } p;
    p.u[0] = f2bf(mv.x * i0); p.u[1] = f2bf(mv.y * i1);
    p.u[2] = f2bf(mv.z * i2); p.u[3] = f2bf(mv.w * i3);
    reinterpret_cast<uint2*>(bb)[(size_t)row * 64 + lane] = p.v;
  }
#pragma unroll
  for (int off = 32; off > 0; off >>= 1) s += __shfl_down(s, off, 64);
  if (lane == 0) musq[row] = s;
}

// -------- chained-tile GEMM: A in LDS once, B in regs, NO in-loop barriers --
// Block = 128 rows x 2048 cols (16 chained col-tiles). Stores of tile ct
// overlap the K-loop of tile ct+1 (only precise vmcnt(N) waits on B-loads,
// never a barrier-drain) -> store engine duty ~95% instead of ~66%.
__global__ __launch_bounds__(256, 2) void gauss_chain(
    const unsigned short* __restrict__ xb, const unsigned short* __restrict__ bb,
    const float* __restrict__ xsq, const float* __restrict__ musq,
    float* __restrict__ out) {
  constexpr int BK = 32;
  constexpr int CHUNK = 128 * BK;                         // shorts per k-chunk (8 KiB)
  __shared__ __align__(16) unsigned short As[8 * CHUNK];  // 64 KiB: all of A-band
  const int tid  = threadIdx.x;
  const int wave = tid >> 6, lane = tid & 63;
  const int wm = wave >> 1, wn = wave & 1;  // 2x2 waves, each 64x64 per tile

  const int b    = blockIdx.x;
  const int xcd  = b & 7;                   // dispatch round-robins XCDs
  const int g    = b >> 3;                  // 0..63
  const int band = (xcd << 5) | (g & 31);   // 0..255: row band, XCD-banded
  const int half = g >> 5;                  // 0..1: which 2048-col half
  const int rowBase  = band * 128;
  const int colBase0 = half * 2048;

  // ---- stage all of A (128 rows x 256 k) once; ONE barrier, no stores yet
  const int srow = lane >> 2;
  const int scol = (lane & 3) * 8;
  const unsigned short* gA0 = xb + (size_t)(rowBase + wave * 16 + srow) * D_ + scol;
  const unsigned short* gA1 = gA0 + (size_t)64 * D_;
  unsigned short* lA0 = &As[(wave * 16) * BK];
  unsigned short* lA1 = &As[(wave * 16 + 64) * BK];
#pragma unroll
  for (int kt = 0; kt < 8; ++kt) {
    async_copy16(lA0 + kt * CHUNK, gA0 + kt * BK);
    async_copy16(lA1 + kt * CHUNK, gA1 + kt * BK);
  }
  __syncthreads();  // drains staging loads (no stores outstanding -> cheap)

  const int fr = lane & 15;        // fragment row (A: m, B: col)
  const int fk = (lane >> 4) * 8;  // k-offset (8 bf16 = 16 B)
  const int q  = lane >> 4, c = lane & 15;

  // hoist per-row xsq (16 values, reused by all 16 col-tiles)
  float xs[4][4];
#pragma unroll
  for (int i = 0; i < 4; ++i)
#pragma unroll
    for (int r = 0; r < 4; ++r)
      xs[i][r] = xsq[rowBase + wm * 64 + i * 16 + q * 4 + r];

  for (int ct = 0; ct < 16; ++ct) {
    const int colBase = colBase0 + ct * 128;
    const unsigned short* Bbase = bb + (size_t)(colBase + wn * 64 + fr) * D_ + fk;
    floatx4 acc[4][4] = {};
#pragma unroll
    for (int kt = 0; kt < 8; ++kt) {
      bf16x8 bfv[4];
#pragma unroll
      for (int j = 0; j < 4; ++j)
        bfv[j] = *reinterpret_cast<const bf16x8*>(Bbase + (size_t)(j * 16) * D_ + kt * BK);
      bf16x8 af[4];
#pragma unroll
      for (int i = 0; i < 4; ++i)
        af[i] = *reinterpret_cast<const bf16x8*>(
            &As[kt * CHUNK + (wm * 64 + i * 16 + fr) * BK + fk]);
#pragma unroll
      for (int i = 0; i < 4; ++i)
#pragma unroll
        for (int j = 0; j < 4; ++j)
          acc[i][j] = __builtin_amdgcn_mfma_f32_16x16x32_bf16(af[i], bfv[j], acc[i][j], 0, 0, 0);
    }
    // epilogue: C/D layout col=lane&15, row=(lane>>4)*4+reg; NT fire-and-forget
    float ms[4];
#pragma unroll
    for (int j = 0; j < 4; ++j) ms[j] = musq[colBase + wn * 64 + j * 16 + c];
#pragma unroll
    for (int i = 0; i < 4; ++i) {
#pragma unroll
      for (int r = 0; r < 4; ++r) {
        const int row = rowBase + wm * 64 + i * 16 + q * 4 + r;
        float* orow = out + (size_t)row * K_ + colBase + wn * 64 + c;
#pragma unroll
        for (int j = 0; j < 4; ++j)
          __builtin_nontemporal_store(__expf(acc[i][j][r] - 0.5f * (xs[i][r] + ms[j])),
                                      orow + j * 16);
      }
    }
  }
}

// ---------------- fallback: fused fp32->bf16 staging (if ws too small) ------
__global__ void gauss_mfma_fused(const float* __restrict__ x, const float* __restrict__ mu,
                                 const float* __restrict__ sd,
                                 const float* __restrict__ xsq, const float* __restrict__ musq,
                                 float* __restrict__ out) {
  constexpr int BM = 128, BN = 128, BK = 32;
  __shared__ __align__(16) unsigned short As[BM * BK];
  __shared__ __align__(16) unsigned short Bs[BN * BK];
  __shared__ float invs[D_];
  const int tid = threadIdx.x;
  invs[tid] = 1.0f / sd[tid];
  const int wave = tid >> 6, lane = tid & 63;
  const int wm = wave >> 1, wn = wave & 1;
  const int rowBase = blockIdx.y * BM;
  const int colBase = blockIdx.x * BN;
  const int srow = tid >> 1;
  const int scol = (tid & 1) * 16;
  const float* gA = x + (size_t)(rowBase + srow) * D_ + scol;
  const float* gB = mu + (size_t)(colBase + srow) * (NC_ * D_) + scol;
  __syncthreads();

  floatx4 acc[4][4] = {};
  const int fr = lane & 15;
  const int fk = (lane >> 4) * 8;

  for (int kt = 0; kt < D_ / BK; ++kt) {
    const int k0 = kt * BK;
    float4 a0 = *(const float4*)(gA + k0);
    float4 a1 = *(const float4*)(gA + k0 + 4);
    float4 a2 = *(const float4*)(gA + k0 + 8);
    float4 a3 = *(const float4*)(gA + k0 + 12);
    float4 b0 = *(const float4*)(gB + k0);
    float4 b1 = *(const float4*)(gB + k0 + 4);
    float4 b2 = *(const float4*)(gB + k0 + 8);
    float4 b3 = *(const float4*)(gB + k0 + 12);
    float fa[16] = {a0.x, a0.y, a0.z, a0.w, a1.x, a1.y, a1.z, a1.w,
                    a2.x, a2.y, a2.z, a2.w, a3.x, a3.y, a3.z, a3.w};
    float fb[16] = {b0.x, b0.y, b0.z, b0.w, b1.x, b1.y, b1.z, b1.w,
                    b2.x, b2.y, b2.z, b2.w, b3.x, b3.y, b3.z, b3.w};
    union { unsigned short u[8]; uint4 v; } pa0, pa1, pb0, pb1;
#pragma unroll
    for (int t = 0; t < 8; ++t) {
      pa0.u[t] = f2bf(fa[t]);
      pa1.u[t] = f2bf(fa[t + 8]);
      pb0.u[t] = f2bf(fb[t] * invs[k0 + scol + t]);
      pb1.u[t] = f2bf(fb[t + 8] * invs[k0 + scol + t + 8]);
    }
    __syncthreads();
    *(uint4*)&As[srow * BK + scol]     = pa0.v;
    *(uint4*)&As[srow * BK + scol + 8] = pa1.v;
    *(uint4*)&Bs[srow * BK + scol]     = pb0.v;
    *(uint4*)&Bs[srow * BK + scol + 8] = pb1.v;
    __syncthreads();
    bf16x8 af[4], bfv[4];
#pragma unroll
    for (int i = 0; i < 4; ++i)
      af[i] = *reinterpret_cast<const bf16x8*>(&As[(wm * 64 + i * 16 + fr) * BK + fk]);
#pragma unroll
    for (int j = 0; j < 4; ++j)
      bfv[j] = *reinterpret_cast<const bf16x8*>(&Bs[(wn * 64 + j * 16 + fr) * BK + fk]);
#pragma unroll
    for (int i = 0; i < 4; ++i)
#pragma unroll
      for (int j = 0; j < 4; ++j)
        acc[i][j] = __builtin_amdgcn_mfma_f32_16x16x32_bf16(af[i], bfv[j], acc[i][j], 0, 0, 0);
  }

  const int q = lane >> 4, c = lane & 15;
  float ms[4];
#pragma unroll
  for (int j = 0; j < 4; ++j) ms[j] = musq[colBase + wn * 64 + j * 16 + c];
#pragma unroll
  for (int i = 0; i < 4; ++i) {
#pragma unroll
    for (int r = 0; r < 4; ++r) {
      const int row = rowBase + wm * 64 + i * 16 + q * 4 + r;
      const float xs = xsq[row];
      float* orow = out + (size_t)row * K_ + colBase + wn * 64 + c;
#pragma unroll
      for (int j = 0; j < 4; ++j)
        orow[j * 16] = __expf(acc[i][j][r] - 0.5f * (xs + ms[j]));
    }
  }
}

// ---------------- last-resort naive (no workspace at all) -------------------
__global__ void gauss_naive(const float* __restrict__ x, const float* __restrict__ mu,
                            const float* __restrict__ sd, float* __restrict__ out) {
  const int k = blockIdx.x * 256 + threadIdx.x;
  const int n = blockIdx.y;
  const float* xr = x + (size_t)n * D_;
  const float* mr = mu + (size_t)k * (NC_ * D_);
  float s = 0.0f;
  for (int d = 0; d < D_; ++d) {
    const float diff = xr[d] - mr[d];
    s += diff * diff / sd[d];
  }
  out[(size_t)n * K_ + k] = __expf(-0.5f * s);
}

extern "C" void kernel_launch(void* const* d_in, const int* in_sizes, int n_in,
                              void* d_out, int out_size, void* d_ws, size_t ws_size,
                              hipStream_t stream) {
  const float* x  = (const float*)d_in[0];
  const float* mu = (const float*)d_in[1];
  const float* sd = (const float*)d_in[2];
  float* out = (float*)d_out;

  const size_t xb_bytes   = (size_t)N_ * D_ * 2;  // 16 MiB
  const size_t bb_bytes   = (size_t)K_ * D_ * 2;  //  2 MiB
  const size_t xsq_bytes  = (size_t)N_ * 4;       // 128 KiB
  const size_t musq_bytes = (size_t)K_ * 4;       //  16 KiB

  if (ws_size >= xb_bytes + bb_bytes + xsq_bytes + musq_bytes) {
    unsigned short* xb = (unsigned short*)d_ws;
    unsigned short* bb = (unsigned short*)((char*)d_ws + xb_bytes);
    float* xsq  = (float*)((char*)d_ws + xb_bytes + bb_bytes);
    float* musq = (float*)((char*)d_ws + xb_bytes + bb_bytes + xsq_bytes);
    prep_x_kern<true><<<N_ / 4, 256, 0, stream>>>(x, sd, xb, xsq);
    prep_mu_kern<true><<<K_ / 4, 256, 0, stream>>>(mu, sd, bb, musq);
    // 512 blocks: 256 row-bands x 2 col-halves; 2 blocks/CU, all co-resident
    gauss_chain<<<512, 256, 0, stream>>>(xb, bb, xsq, musq, out);
  } else if (ws_size >= xsq_bytes + musq_bytes) {
    float* xsq  = (float*)d_ws;
    float* musq = (float*)((char*)d_ws + xsq_bytes);
    prep_x_kern<false><<<N_ / 4, 256, 0, stream>>>(x, sd, nullptr, xsq);
    prep_mu_kern<false><<<K_ / 4, 256, 0, stream>>>(mu, sd, nullptr, musq);
    gauss_mfma_fused<<<dim3(K_ / 128, N_ / 128), 256, 0, stream>>>(x, mu, sd, xsq, musq, out);
  } else {
    gauss_naive<<<dim3(K_ / 256, N_), 256, 0, stream>>>(x, mu, sd, out);
  }
}

// Round 11
// 579.553 us; speedup vs baseline: 1.1219x; 1.1219x over previous
//
#include <hip/hip_runtime.h>

#define N_ 32768
#define K_ 4096
#define NC_ 4
#define D_ 256

using floatx4 = __attribute__((ext_vector_type(4))) float;
using bf16x8  = __attribute__((ext_vector_type(8))) short;

__device__ __forceinline__ unsigned short f2bf(float f) {
  union { float f; unsigned u; } a;
  a.f = f;
  unsigned u = a.u;
  u += 0x7fffu + ((u >> 16) & 1u);  // round-to-nearest-even
  return (unsigned short)(u >> 16);
}

__device__ __forceinline__ void async_copy16(void* lds, const void* g) {
  __builtin_amdgcn_global_load_lds(
      (__attribute__((address_space(1))) void*)(g),
      (__attribute__((address_space(3))) void*)(lds),
      16, 0, 0);
}

// ---------------- prep kernels: bf16 conversion + weighted row norms --------
template <bool WRITE_BF>
__global__ void prep_x_kern(const float* __restrict__ x, const float* __restrict__ sd,
                            unsigned short* __restrict__ xb, float* __restrict__ xsq) {
  const int lane = threadIdx.x & 63;
  const int row  = blockIdx.x * 4 + (threadIdx.x >> 6);
  const float4 xv = reinterpret_cast<const float4*>(x + (size_t)row * D_)[lane];
  const float4 sv = reinterpret_cast<const float4*>(sd)[lane];
  const float i0 = 1.0f / sv.x, i1 = 1.0f / sv.y, i2 = 1.0f / sv.z, i3 = 1.0f / sv.w;
  float s = xv.x * xv.x * i0 + xv.y * xv.y * i1 + xv.z * xv.z * i2 + xv.w * xv.w * i3;
  if (WRITE_BF) {
    union { unsigned short u[4]; uint2 v; } p;
    p.u[0] = f2bf(xv.x); p.u[1] = f2bf(xv.y); p.u[2] = f2bf(xv.z); p.u[3] = f2bf(xv.w);
    reinterpret_cast<uint2*>(xb)[(size_t)row * 64 + lane] = p.v;
  }
#pragma unroll
  for (int off = 32; off > 0; off >>= 1) s += __shfl_down(s, off, 64);
  if (lane == 0) xsq[row] = s;
}

template <bool WRITE_BF>
__global__ void prep_mu_kern(const float* __restrict__ mu, const float* __restrict__ sd,
                             unsigned short* __restrict__ bb, float* __restrict__ musq) {
  const int lane = threadIdx.x & 63;
  const int row  = blockIdx.x * 4 + (threadIdx.x >> 6);
  const float4 mv = reinterpret_cast<const float4*>(mu + (size_t)row * (NC_ * D_))[lane];
  const float4 sv = reinterpret_cast<const float4*>(sd)[lane];
  const float i0 = 1.0f / sv.x, i1 = 1.0f / sv.y, i2 = 1.0f / sv.z, i3 = 1.0f / sv.w;
  float s = mv.x * mv.x * i0 + mv.y * mv.y * i1 + mv.z * mv.z * i2 + mv.w * mv.w * i3;
  if (WRITE_BF) {
    union { unsigned short u[4]; uint2 v; } p;
    p.u[0] = f2bf(mv.x * i0); p.u[1] = f2bf(mv.y * i1);
    p.u[2] = f2bf(mv.z * i2); p.u[3] = f2bf(mv.w * i3);
    reinterpret_cast<uint2*>(bb)[(size_t)row * 64 + lane] = p.v;
  }
#pragma unroll
  for (int off = 32; off > 0; off >>= 1) s += __shfl_down(s, off, 64);
  if (lane == 0) musq[row] = s;
}

// ------ small-block MFMA GEMM: 128x64 tile, 2 waves, 6 blocks/CU ------------
// C[n,k] = expf( x·b^T - 0.5*(xsq[n] + musq[k]) ),  b = mu0 * inv_std (bf16)
// R11: same K-loop/epilogue/NT/col-fast swizzle as R8, but half-size blocks ->
// 6 independent phase slots per CU so write-silent K-loop phases decorrelate
// and the store engine's duty cycle rises.
__global__ __launch_bounds__(128, 3) void gauss_mfma(
    const unsigned short* __restrict__ xb, const unsigned short* __restrict__ bb,
    const float* __restrict__ xsq, const float* __restrict__ musq,
    float* __restrict__ out) {
  constexpr int BM = 128, BN = 64, BK = 32;
  // K-loop: As (8 KiB) | Bs (4 KiB). Epilogue reuses first 8 KiB as two
  // wave-private 4 KiB transpose patches (no barrier needed: each wave's patch
  // overlaps exactly the A rows only that wave reads).
  __shared__ __align__(16) unsigned short smem[(BM + BN) * BK];
  unsigned short* As = smem;
  unsigned short* Bs = smem + BM * BK;
  const int tid  = threadIdx.x;
  const int wave = tid >> 6, lane = tid & 63;  // 2 waves: wave = row-half

  const int b   = blockIdx.x;
  const int xcd = b & 7;                    // dispatch round-robins XCDs
  const int g   = b >> 3;                   // 0..2047 per XCD
  const int colT = g & 63;                  // FAST: consecutive blocks -> cols
  const int rowT = (xcd << 5) | (g >> 6);   // 0..255, XCD-banded
  const int rowBase = rowT * BM;
  const int colBase = colT * BN;

  // staging: global_load_lds, lds dst = wave-uniform base + lane*16B
  const int srow = lane >> 2;
  const int scol = (lane & 3) * 8;
  // per wave: 4 A-chunks (16 rows each, rows wave*64 + c*16) + 2 B-chunks
  const unsigned short* gA = xb + (size_t)(rowBase + wave * 64 + srow) * D_ + scol;
  const unsigned short* gB = bb + (size_t)(colBase + wave * 32 + srow) * D_ + scol;
  unsigned short* lA = &As[(wave * 64) * BK];
  unsigned short* lB = &Bs[(wave * 32) * BK];

  floatx4 acc[4][4] = {};
  const int fr = lane & 15;        // A: row m / B: col n
  const int fk = (lane >> 4) * 8;  // k-chunk (8 contiguous bf16 = 16B)

#pragma unroll
  for (int kt = 0; kt < D_ / BK; ++kt) {
    const int ko = kt * BK;
    __syncthreads();  // everyone done reading previous tile
#pragma unroll
    for (int c = 0; c < 4; ++c)
      async_copy16(lA + (c * 16) * BK, gA + (size_t)(c * 16) * D_ + ko);
#pragma unroll
    for (int c = 0; c < 2; ++c)
      async_copy16(lB + (c * 16) * BK, gB + (size_t)(c * 16) * D_ + ko);
    __syncthreads();  // drains vmcnt(0) before s_barrier
    bf16x8 af[4], bfv[4];
#pragma unroll
    for (int i = 0; i < 4; ++i)
      af[i] = *reinterpret_cast<const bf16x8*>(&As[(wave * 64 + i * 16 + fr) * BK + fk]);
#pragma unroll
    for (int j = 0; j < 4; ++j)
      bfv[j] = *reinterpret_cast<const bf16x8*>(&Bs[(j * 16 + fr) * BK + fk]);
#pragma unroll
    for (int i = 0; i < 4; ++i)
#pragma unroll
      for (int j = 0; j < 4; ++j)
        acc[i][j] = __builtin_amdgcn_mfma_f32_16x16x32_bf16(af[i], bfv[j], acc[i][j], 0, 0, 0);
  }

  // ---- epilogue: exp + per-wave LDS transpose -> 1 KiB NT stores
  // C/D layout: col=lane&15, row=(lane>>4)*4+reg. Patch is wave-private and
  // aliases only this wave's A rows -> no barrier.
  float* patch = reinterpret_cast<float*>(smem) + wave * 1024;  // 16 rows x 64 cols
  const int q = lane >> 4, c = lane & 15;
  float ms[4];
#pragma unroll
  for (int j = 0; j < 4; ++j) ms[j] = musq[colBase + j * 16 + c];

#pragma unroll
  for (int i = 0; i < 4; ++i) {
#pragma unroll
    for (int r = 0; r < 4; ++r) {
      const float xs = xsq[rowBase + wave * 64 + i * 16 + q * 4 + r];
#pragma unroll
      for (int j = 0; j < 4; ++j)
        patch[(q * 4 + r) * 64 + j * 16 + c] = __expf(acc[i][j][r] - 0.5f * (xs + ms[j]));
    }
    // read-back: lane l -> dwords 4l..4l+3 (conflict-free); 1 KiB/instr NT
    // stores (4 rows x 256 B)
#pragma unroll
    for (int r2 = 0; r2 < 4; ++r2) {
      const floatx4 v = *reinterpret_cast<const floatx4*>(&patch[r2 * 256 + lane * 4]);
      const int row = rowBase + wave * 64 + i * 16 + r2 * 4 + (lane >> 4);
      const int col = colBase + (lane & 15) * 4;
      __builtin_nontemporal_store(v, reinterpret_cast<floatx4*>(out + (size_t)row * K_ + col));
    }
  }
}

// ---------------- fallback: fused fp32->bf16 staging (if ws too small) ------
__global__ void gauss_mfma_fused(const float* __restrict__ x, const float* __restrict__ mu,
                                 const float* __restrict__ sd,
                                 const float* __restrict__ xsq, const float* __restrict__ musq,
                                 float* __restrict__ out) {
  constexpr int BM = 128, BN = 128, BK = 32;
  __shared__ __align__(16) unsigned short As[BM * BK];
  __shared__ __align__(16) unsigned short Bs[BN * BK];
  __shared__ float invs[D_];
  const int tid = threadIdx.x;
  invs[tid] = 1.0f / sd[tid];
  const int wave = tid >> 6, lane = tid & 63;
  const int wm = wave >> 1, wn = wave & 1;
  const int rowBase = blockIdx.y * BM;
  const int colBase = blockIdx.x * BN;
  const int srow = tid >> 1;
  const int scol = (tid & 1) * 16;
  const float* gA = x + (size_t)(rowBase + srow) * D_ + scol;
  const float* gB = mu + (size_t)(colBase + srow) * (NC_ * D_) + scol;
  __syncthreads();

  floatx4 acc[4][4] = {};
  const int fr = lane & 15;
  const int fk = (lane >> 4) * 8;

  for (int kt = 0; kt < D_ / BK; ++kt) {
    const int k0 = kt * BK;
    float4 a0 = *(const float4*)(gA + k0);
    float4 a1 = *(const float4*)(gA + k0 + 4);
    float4 a2 = *(const float4*)(gA + k0 + 8);
    float4 a3 = *(const float4*)(gA + k0 + 12);
    float4 b0 = *(const float4*)(gB + k0);
    float4 b1 = *(const float4*)(gB + k0 + 4);
    float4 b2 = *(const float4*)(gB + k0 + 8);
    float4 b3 = *(const float4*)(gB + k0 + 12);
    float fa[16] = {a0.x, a0.y, a0.z, a0.w, a1.x, a1.y, a1.z, a1.w,
                    a2.x, a2.y, a2.z, a2.w, a3.x, a3.y, a3.z, a3.w};
    float fb[16] = {b0.x, b0.y, b0.z, b0.w, b1.x, b1.y, b1.z, b1.w,
                    b2.x, b2.y, b2.z, b2.w, b3.x, b3.y, b3.z, b3.w};
    union { unsigned short u[8]; uint4 v; } pa0, pa1, pb0, pb1;
#pragma unroll
    for (int t = 0; t < 8; ++t) {
      pa0.u[t] = f2bf(fa[t]);
      pa1.u[t] = f2bf(fa[t + 8]);
      pb0.u[t] = f2bf(fb[t] * invs[k0 + scol + t]);
      pb1.u[t] = f2bf(fb[t + 8] * invs[k0 + scol + t + 8]);
    }
    __syncthreads();
    *(uint4*)&As[srow * BK + scol]     = pa0.v;
    *(uint4*)&As[srow * BK + scol + 8] = pa1.v;
    *(uint4*)&Bs[srow * BK + scol]     = pb0.v;
    *(uint4*)&Bs[srow * BK + scol + 8] = pb1.v;
    __syncthreads();
    bf16x8 af[4], bfv[4];
#pragma unroll
    for (int i = 0; i < 4; ++i)
      af[i] = *reinterpret_cast<const bf16x8*>(&As[(wm * 64 + i * 16 + fr) * BK + fk]);
#pragma unroll
    for (int j = 0; j < 4; ++j)
      bfv[j] = *reinterpret_cast<const bf16x8*>(&Bs[(wn * 64 + j * 16 + fr) * BK + fk]);
#pragma unroll
    for (int i = 0; i < 4; ++i)
#pragma unroll
      for (int j = 0; j < 4; ++j)
        acc[i][j] = __builtin_amdgcn_mfma_f32_16x16x32_bf16(af[i], bfv[j], acc[i][j], 0, 0, 0);
  }

  const int q = lane >> 4, c = lane & 15;
  float ms[4];
#pragma unroll
  for (int j = 0; j < 4; ++j) ms[j] = musq[colBase + wn * 64 + j * 16 + c];
#pragma unroll
  for (int i = 0; i < 4; ++i) {
#pragma unroll
    for (int r = 0; r < 4; ++r) {
      const int row = rowBase + wm * 64 + i * 16 + q * 4 + r;
      const float xs = xsq[row];
      float* orow = out + (size_t)row * K_ + colBase + wn * 64 + c;
#pragma unroll
      for (int j = 0; j < 4; ++j)
        orow[j * 16] = __expf(acc[i][j][r] - 0.5f * (xs + ms[j]));
    }
  }
}

// ---------------- last-resort naive (no workspace at all) -------------------
__global__ void gauss_naive(const float* __restrict__ x, const float* __restrict__ mu,
                            const float* __restrict__ sd, float* __restrict__ out) {
  const int k = blockIdx.x * 256 + threadIdx.x;
  const int n = blockIdx.y;
  const float* xr = x + (size_t)n * D_;
  const float* mr = mu + (size_t)k * (NC_ * D_);
  float s = 0.0f;
  for (int d = 0; d < D_; ++d) {
    const float diff = xr[d] - mr[d];
    s += diff * diff / sd[d];
  }
  out[(size_t)n * K_ + k] = __expf(-0.5f * s);
}

extern "C" void kernel_launch(void* const* d_in, const int* in_sizes, int n_in,
                              void* d_out, int out_size, void* d_ws, size_t ws_size,
                              hipStream_t stream) {
  const float* x  = (const float*)d_in[0];
  const float* mu = (const float*)d_in[1];
  const float* sd = (const float*)d_in[2];
  float* out = (float*)d_out;

  const size_t xb_bytes   = (size_t)N_ * D_ * 2;  // 16 MiB
  const size_t bb_bytes   = (size_t)K_ * D_ * 2;  //  2 MiB
  const size_t xsq_bytes  = (size_t)N_ * 4;       // 128 KiB
  const size_t musq_bytes = (size_t)K_ * 4;       //  16 KiB

  if (ws_size >= xb_bytes + bb_bytes + xsq_bytes + musq_bytes) {
    unsigned short* xb = (unsigned short*)d_ws;
    unsigned short* bb = (unsigned short*)((char*)d_ws + xb_bytes);
    float* xsq  = (float*)((char*)d_ws + xb_bytes + bb_bytes);
    float* musq = (float*)((char*)d_ws + xb_bytes + bb_bytes + xsq_bytes);
    prep_x_kern<true><<<N_ / 4, 256, 0, stream>>>(x, sd, xb, xsq);
    prep_mu_kern<true><<<K_ / 4, 256, 0, stream>>>(mu, sd, bb, musq);
    // 16384 blocks of 128 threads: 256 row-tiles x 64 col-tiles (128x64 each)
    gauss_mfma<<<(N_ / 128) * (K_ / 64), 128, 0, stream>>>(xb, bb, xsq, musq, out);
  } else if (ws_size >= xsq_bytes + musq_bytes) {
    float* xsq  = (float*)d_ws;
    float* musq = (float*)((char*)d_ws + xsq_bytes);
    prep_x_kern<false><<<N_ / 4, 256, 0, stream>>>(x, sd, nullptr, xsq);
    prep_mu_kern<false><<<K_ / 4, 256, 0, stream>>>(mu, sd, nullptr, musq);
    gauss_mfma_fused<<<dim3(K_ / 128, N_ / 128), 256, 0, stream>>>(x, mu, sd, xsq, musq, out);
  } else {
    gauss_naive<<<dim3(K_ / 256, N_), 256, 0, stream>>>(x, mu, sd, out);
  }
}